// Round 17
// baseline (226.004 us; speedup 1.0000x reference)
//
#include <hip/hip_runtime.h>

#define DEVI __device__ __forceinline__

typedef short bf16x8 __attribute__((ext_vector_type(8)));
typedef short bf16x4 __attribute__((ext_vector_type(4)));
typedef float f32x4 __attribute__((ext_vector_type(4)));

constexpr int Bb = 8, TX = 1024, TC = 2048, CC = 512, NH = 8, HD = 64;
constexpr float LOG2E = 1.44269504f;

// fp32 -> bf16 round-to-nearest-even (values here are well-behaved, no NaN/Inf)
DEVI unsigned short f2bf(float f) {
  union { float f; unsigned u; } v; v.f = f;
  return (unsigned short)((v.u + 0x7FFFu + ((v.u >> 16) & 1u)) >> 16);
}

// packed f32x2 -> bf16x2 (low = lo, high = hi); no builtin on gfx950 (T12)
DEVI unsigned cvtpk(float lo, float hi) {
  unsigned r;
  asm("v_cvt_pk_bf16_f32 %0, %1, %2" : "=v"(r) : "v"(lo), "v"(hi));
  return r;
}

DEVI f32x4 mfma16(bf16x8 a, bf16x8 b, f32x4 c) {
  return __builtin_amdgcn_mfma_f32_16x16x32_bf16(a, b, c, 0, 0, 0);
}

DEVI f32x4 zero4() { f32x4 z = {0.f, 0.f, 0.f, 0.f}; return z; }

DEVI float max3f(float a, float b, float c) { return fmaxf(fmaxf(a, b), c); }

// async global->LDS, 16B per lane; LDS dest is wave-uniform base + lane*16,
// global source is per-lane (swizzled source = swizzled LDS layout, m173)
DEVI void gload_lds16(const unsigned short* g, unsigned short* l) {
  __builtin_amdgcn_global_load_lds(
      (const __attribute__((address_space(1))) void*)g,
      (__attribute__((address_space(3))) void*)l, 16, 0, 0);
}

// ---------------------------------------------------------------------------
// Fused fp32 -> bf16 convert for all 6 regions in ONE launch.
// ---------------------------------------------------------------------------
DEVI void cvt_region(const float* __restrict__ src,
                     unsigned short* __restrict__ dst, int n8, int i0, int stride) {
  for (int i = i0; i < n8; i += stride) {
    f32x4 a = *(const f32x4*)(src + (size_t)i * 8);
    f32x4 b = *(const f32x4*)(src + (size_t)i * 8 + 4);
    bf16x8 v;
#pragma unroll
    for (int j = 0; j < 4; j++) {
      v[j] = (short)f2bf(a[j]);
      v[j + 4] = (short)f2bf(b[j]);
    }
    *(bf16x8*)(dst + (size_t)i * 8) = v;
  }
}

__global__ __launch_bounds__(256) void cvt_all(
    const float* __restrict__ s0, unsigned short* __restrict__ d0, int n0,
    const float* __restrict__ s1, unsigned short* __restrict__ d1, int n1,
    const float* __restrict__ s2, unsigned short* __restrict__ d2, int n2,
    const float* __restrict__ s3, unsigned short* __restrict__ d3, int n3,
    const float* __restrict__ s4, unsigned short* __restrict__ d4, int n4,
    const float* __restrict__ s5, unsigned short* __restrict__ d5, int n5) {
  const int i0 = blockIdx.x * 256 + threadIdx.x;
  const int stride = gridDim.x * 256;
  cvt_region(s0, d0, n0, i0, stride);
  cvt_region(s1, d1, n1, i0, stride);
  cvt_region(s2, d2, n2, i0, stride);
  cvt_region(s3, d3, n3, i0, stride);
  cvt_region(s4, d4, n4, i0, stride);
  cvt_region(s5, d5, n5, i0, stride);
}

// ---------------------------------------------------------------------------
// 128x128-tile NT GEMM (m93/m97 ladder structure), all-bf16 inputs:
// out[r][c] = (sum_k A[r][k]*W[c][k] + bias[c]) * scale
// BK=32, 256 threads = 4 waves in 2x2 (each 64x64 = 4x4 MFMA frags).
// global_load_lds width=16 into linear dbuf LDS, pre-swizzled SOURCE
// (slot ^= (row>>1)&3, same involution on ds_read). One barrier per K-step;
// stage for kt+1 issued right AFTER the barrier (drain a full phase away).
// MODE 0: out bf16 permuted to (b,h,t,d).  MODE 1: out fp32 (r*512+c).
// ---------------------------------------------------------------------------
template <int MODE>
__global__ __launch_bounds__(256, 3) void gemm128(
    const unsigned short* __restrict__ A, const unsigned short* __restrict__ W,
    const float* __restrict__ bias, void* __restrict__ outp, int tlog2, float scale) {
  __shared__ __align__(16) unsigned short As[2][128 * 32];
  __shared__ __align__(16) unsigned short Bs[2][128 * 32];

  const int tid = threadIdx.x;
  const int wid = tid >> 6, l = tid & 63, l15 = l & 15, lhi = l >> 4;
  const int wm = wid >> 1, wn = wid & 1;
  const int mbase = blockIdx.y * 128, nbase = blockIdx.x * 128;

  f32x4 acc[4][4];
#pragma unroll
  for (int i = 0; i < 4; i++)
#pragma unroll
    for (int j = 0; j < 4; j++) acc[i][j] = zero4();

  auto stage = [&](int buf, int k0) {
#pragma unroll
    for (int i = 0; i < 2; i++) {
      const int u = wid * 128 + i * 64 + l;
      const int row = u >> 2;
      const int gc = ((u & 3) ^ ((row >> 1) & 3)) * 8;
      const int lo = (wid * 128 + i * 64) * 8;
      gload_lds16(A + (size_t)(mbase + row) * CC + k0 + gc, &As[buf][lo]);
      gload_lds16(W + (size_t)(nbase + row) * CC + k0 + gc, &Bs[buf][lo]);
    }
  };

  stage(0, 0);

  const int sA = (lhi ^ ((l15 >> 1) & 3)) << 3;

  constexpr int NK = CC / 32;
  for (int kt = 0; kt < NK; kt++) {
    const int cur = kt & 1;
    __syncthreads();
    if (kt + 1 < NK) stage(cur ^ 1, (kt + 1) * 32);

    bf16x8 af[4], bfr[4];
#pragma unroll
    for (int mi = 0; mi < 4; mi++)
      af[mi] = *(const bf16x8*)&As[cur][(wm * 64 + mi * 16 + l15) * 32 + sA];
#pragma unroll
    for (int ni = 0; ni < 4; ni++)
      bfr[ni] = *(const bf16x8*)&Bs[cur][(wn * 64 + ni * 16 + l15) * 32 + sA];
#pragma unroll
    for (int mi = 0; mi < 4; mi++)
#pragma unroll
      for (int ni = 0; ni < 4; ni++)
        acc[mi][ni] = mfma16(af[mi], bfr[ni], acc[mi][ni]);
  }

#pragma unroll
  for (int mi = 0; mi < 4; mi++)
#pragma unroll
    for (int ni = 0; ni < 4; ni++)
#pragma unroll
      for (int r = 0; r < 4; r++) {
        int grow = mbase + wm * 64 + mi * 16 + 4 * lhi + r;
        int gcol = nbase + wn * 64 + ni * 16 + l15;
        float val = (acc[mi][ni][r] + bias[gcol]) * scale;
        if (MODE == 0) {
          int T = 1 << tlog2;
          int bq = grow >> tlog2, tt = grow & (T - 1);
          int h = gcol >> 6, d = gcol & 63;
          size_t oidx = ((size_t)(bq * NH + h) * T + tt) * HD + d;
          ((unsigned short*)outp)[oidx] = f2bf(val);
        } else {
          ((float*)outp)[(size_t)grow * CC + gcol] = val;
        }
      }
}

// ---------------------------------------------------------------------------
// Fused K+V projection, 128x128 tile + global_load_lds (same structure as
// gemm128): one A (ctx) tile feeds both Wk and Wv B-tiles (32 MFMA/K-step).
// K epilogue -> (b,h,t,d) bf16; V epilogue -> V^T (b,h,d,t) bf16.
// ---------------------------------------------------------------------------
__global__ __launch_bounds__(256, 2) void kv_gemm128(
    const unsigned short* __restrict__ A, const unsigned short* __restrict__ Wk,
    const unsigned short* __restrict__ Wv, const float* __restrict__ bk,
    const float* __restrict__ bv, unsigned short* __restrict__ k_out,
    unsigned short* __restrict__ v_out) {
  __shared__ __align__(16) unsigned short As[2][128 * 32];
  __shared__ __align__(16) unsigned short Bks[2][128 * 32];
  __shared__ __align__(16) unsigned short Bvs[2][128 * 32];

  const int tid = threadIdx.x;
  const int wid = tid >> 6, l = tid & 63, l15 = l & 15, lhi = l >> 4;
  const int wm = wid >> 1, wn = wid & 1;
  const int mbase = blockIdx.y * 128, nbase = blockIdx.x * 128;

  f32x4 acck[4][4], accv[4][4];
#pragma unroll
  for (int i = 0; i < 4; i++)
#pragma unroll
    for (int j = 0; j < 4; j++) { acck[i][j] = zero4(); accv[i][j] = zero4(); }

  auto stage = [&](int buf, int k0) {
#pragma unroll
    for (int i = 0; i < 2; i++) {
      const int u = wid * 128 + i * 64 + l;
      const int row = u >> 2;
      const int gc = ((u & 3) ^ ((row >> 1) & 3)) * 8;
      const int lo = (wid * 128 + i * 64) * 8;
      gload_lds16(A + (size_t)(mbase + row) * CC + k0 + gc, &As[buf][lo]);
      gload_lds16(Wk + (size_t)(nbase + row) * CC + k0 + gc, &Bks[buf][lo]);
      gload_lds16(Wv + (size_t)(nbase + row) * CC + k0 + gc, &Bvs[buf][lo]);
    }
  };

  stage(0, 0);

  const int sA = (lhi ^ ((l15 >> 1) & 3)) << 3;

  constexpr int NK = CC / 32;
  for (int kt = 0; kt < NK; kt++) {
    const int cur = kt & 1;
    __syncthreads();
    if (kt + 1 < NK) stage(cur ^ 1, (kt + 1) * 32);

    bf16x8 af[4], kf[4], vf[4];
#pragma unroll
    for (int mi = 0; mi < 4; mi++)
      af[mi] = *(const bf16x8*)&As[cur][(wm * 64 + mi * 16 + l15) * 32 + sA];
#pragma unroll
    for (int ni = 0; ni < 4; ni++) {
      kf[ni] = *(const bf16x8*)&Bks[cur][(wn * 64 + ni * 16 + l15) * 32 + sA];
      vf[ni] = *(const bf16x8*)&Bvs[cur][(wn * 64 + ni * 16 + l15) * 32 + sA];
    }
#pragma unroll
    for (int mi = 0; mi < 4; mi++)
#pragma unroll
      for (int ni = 0; ni < 4; ni++) {
        acck[mi][ni] = mfma16(af[mi], kf[ni], acck[mi][ni]);
        accv[mi][ni] = mfma16(af[mi], vf[ni], accv[mi][ni]);
      }
  }

#pragma unroll
  for (int mi = 0; mi < 4; mi++)
#pragma unroll
    for (int ni = 0; ni < 4; ni++)
#pragma unroll
      for (int r = 0; r < 4; r++) {
        int grow = mbase + wm * 64 + mi * 16 + 4 * lhi + r;
        int gcol = nbase + wn * 64 + ni * 16 + l15;
        int bq = grow >> 11, tt = grow & (TC - 1);
        int h = gcol >> 6, d = gcol & 63;
        float kv = acck[mi][ni][r] + bk[gcol];
        float vv = accv[mi][ni][r] + bv[gcol];
        k_out[((size_t)(bq * NH + h) * TC + tt) * HD + d] = f2bf(kv);
        v_out[((size_t)(bq * NH + h) * HD + d) * TC + tt] = f2bf(vv);
      }
}

// ---------------------------------------------------------------------------
// Flash attention fwd v9 (unchanged): 8 waves; swapped-QK^T in-register
// softmax; ones-MFMA row-sum; max3 tree; XOR-swizzled K/V LDS; exp2 softmax;
// defer-max; setprio on MFMA clusters; one barrier/iter.
// ---------------------------------------------------------------------------
__global__ __launch_bounds__(512) void attn_fwd(
    const unsigned short* __restrict__ Qw, const unsigned short* __restrict__ Kw,
    const unsigned short* __restrict__ Vtw, unsigned short* __restrict__ y_pre,
    float* __restrict__ m_ws, float* __restrict__ il_ws) {
  __shared__ __align__(16) unsigned short ktl[2][64 * 64];  // [buf][key][d] swz
  __shared__ __align__(16) unsigned short vtl[2][64 * 64];  // [buf][d][key] swz

  const int tid = threadIdx.x;
  const int wid = tid >> 6, l = tid & 63, l15 = l & 15, lhi = l >> 4;
  const int qg = blockIdx.x, h = blockIdx.y, b = blockIdx.z;
  const int qbase = qg * 128 + wid * 16;

  const unsigned short* Qh = Qw + (size_t)(b * NH + h) * TX * HD;
  const unsigned short* Kh = Kw + (size_t)(b * NH + h) * TC * HD;
  const unsigned short* Vt = Vtw + (size_t)(b * NH + h) * TC * HD;  // (d, t)

  bf16x8 aq0 = *(const bf16x8*)(Qh + (size_t)(qbase + l15) * HD + lhi * 8);
  bf16x8 aq1 = *(const bf16x8*)(Qh + (size_t)(qbase + l15) * HD + 32 + lhi * 8);

  bf16x8 ones;
#pragma unroll
  for (int j = 0; j < 8; j++) ones[j] = (short)0x3F80;  // bf16 1.0

  f32x4 accy[4];
#pragma unroll
  for (int db = 0; db < 4; db++) accy[db] = zero4();
  f32x4 accl = zero4();  // P-row-sum accumulator (ones-MFMA)
  float mrun = -1e30f;

  const int sl0 = l15 + ((lhi & 1) << 5);
  const int sl1 = sl0 + 16;
  const bool sel = ((lhi >> 1) & 1) != 0;

  const int rs0 = (lhi ^ (l15 & 7)) << 3;
  const int rs1 = ((lhi ^ 4) ^ (l15 & 7)) << 3;

  const int sr = tid >> 3;
  const int ssw = ((tid & 7) ^ (sr & 7)) << 3;
  const int sc0 = (tid & 7) * 8;

  bf16x8 kr = *(const bf16x8*)(Kh + (size_t)sr * HD + sc0);
  bf16x8 vp = *(const bf16x8*)(Vt + (size_t)sr * TC + sc0);
  *(bf16x8*)&ktl[0][sr * 64 + ssw] = kr;
  *(bf16x8*)&vtl[0][sr * 64 + ssw] = vp;
  __syncthreads();

  constexpr int NT = TC / 64;
  for (int kt = 0; kt < NT; kt++) {
    const int cur = kt & 1;

    if (kt + 1 < NT) {
      const int keyn = (kt + 1) * 64;
      kr = *(const bf16x8*)(Kh + (size_t)(keyn + sr) * HD + sc0);
      vp = *(const bf16x8*)(Vt + (size_t)sr * TC + keyn + sc0);
    }

    f32x4 s[4];
    __builtin_amdgcn_s_setprio(1);
#pragma unroll
    for (int kb = 0; kb < 4; kb++) {
      bf16x8 bk0 = *(const bf16x8*)&ktl[cur][(kb * 16 + l15) * 64 + rs0];
      bf16x8 bk1 = *(const bf16x8*)&ktl[cur][(kb * 16 + l15) * 64 + rs1];
      f32x4 a = zero4();
      a = mfma16(bk0, aq0, a);
      a = mfma16(bk1, aq1, a);
      s[kb] = a;
    }
    __builtin_amdgcn_s_setprio(0);

    float t0 = max3f(s[0][0], s[0][1], s[0][2]);
    float t1 = max3f(s[0][3], s[1][0], s[1][1]);
    float t2 = max3f(s[1][2], s[1][3], s[2][0]);
    float t3 = max3f(s[2][1], s[2][2], s[2][3]);
    float t4 = max3f(s[3][0], s[3][1], s[3][2]);
    float mx = fmaxf(max3f(t0, t1, t2), max3f(t3, t4, s[3][3]));
    mx = fmaxf(mx, __shfl_xor(mx, 16));
    mx = fmaxf(mx, __shfl_xor(mx, 32));

    if (__any(mx - mrun > 7.0f)) {
      float mn = fmaxf(mrun, mx);
      float sc = exp2f(mrun - mn);
      mrun = mn;
#pragma unroll
      for (int r = 0; r < 4; r++) accl[r] *= sc;
#pragma unroll
      for (int db = 0; db < 4; db++)
#pragma unroll
        for (int r = 0; r < 4; r++) accy[db][r] *= sc;
    }

    float p[4][4];
#pragma unroll
    for (int kb = 0; kb < 4; kb++)
#pragma unroll
      for (int r = 0; r < 4; r++) p[kb][r] = exp2f(s[kb][r] - mrun);

    unsigned pkw[4][2];
#pragma unroll
    for (int kb = 0; kb < 4; kb++) {
      pkw[kb][0] = cvtpk(p[kb][0], p[kb][1]);
      pkw[kb][1] = cvtpk(p[kb][2], p[kb][3]);
    }
    unsigned a00 = (unsigned)__shfl((int)pkw[0][0], sl0);
    unsigned a01 = (unsigned)__shfl((int)pkw[0][1], sl0);
    unsigned a10 = (unsigned)__shfl((int)pkw[1][0], sl0);
    unsigned a11 = (unsigned)__shfl((int)pkw[1][1], sl0);
    unsigned c00 = (unsigned)__shfl((int)pkw[0][0], sl1);
    unsigned c01 = (unsigned)__shfl((int)pkw[0][1], sl1);
    unsigned c10 = (unsigned)__shfl((int)pkw[1][0], sl1);
    unsigned c11 = (unsigned)__shfl((int)pkw[1][1], sl1);
    unsigned e00 = (unsigned)__shfl((int)pkw[2][0], sl0);
    unsigned e01 = (unsigned)__shfl((int)pkw[2][1], sl0);
    unsigned e10 = (unsigned)__shfl((int)pkw[3][0], sl0);
    unsigned e11 = (unsigned)__shfl((int)pkw[3][1], sl0);
    unsigned g00 = (unsigned)__shfl((int)pkw[2][0], sl1);
    unsigned g01 = (unsigned)__shfl((int)pkw[2][1], sl1);
    unsigned g10 = (unsigned)__shfl((int)pkw[3][0], sl1);
    unsigned g11 = (unsigned)__shfl((int)pkw[3][1], sl1);
    union { unsigned u[4]; bf16x8 v; } B0, B1;
    B0.u[0] = sel ? a10 : a00;
    B0.u[1] = sel ? a11 : a01;
    B0.u[2] = sel ? c10 : c00;
    B0.u[3] = sel ? c11 : c01;
    B1.u[0] = sel ? e10 : e00;
    B1.u[1] = sel ? e11 : e01;
    B1.u[2] = sel ? g10 : g00;
    B1.u[3] = sel ? g11 : g01;

    __builtin_amdgcn_s_setprio(1);
#pragma unroll
    for (int db = 0; db < 4; db++) {
      bf16x8 bv0 = *(const bf16x8*)&vtl[cur][(db * 16 + l15) * 64 + rs0];
      bf16x8 bv1 = *(const bf16x8*)&vtl[cur][(db * 16 + l15) * 64 + rs1];
      accy[db] = mfma16(bv0, B0.v, accy[db]);
      accy[db] = mfma16(bv1, B1.v, accy[db]);
    }
    accl = mfma16(ones, B0.v, accl);
    accl = mfma16(ones, B1.v, accl);
    __builtin_amdgcn_s_setprio(0);

    if (kt + 1 < NT) {
      const int nxt = cur ^ 1;
      *(bf16x8*)&ktl[nxt][sr * 64 + ssw] = kr;
      *(bf16x8*)&vtl[nxt][sr * 64 + ssw] = vp;
    }
    __syncthreads();
  }

  const float il = 1.f / accl[0];

#pragma unroll
  for (int db = 0; db < 4; db++) {
    bf16x4 o;
#pragma unroll
    for (int r = 0; r < 4; r++) o[r] = (short)f2bf(accy[db][r] * il);
    *(bf16x4*)(y_pre + (size_t)(b * TX + qbase + l15) * CC + h * HD + db * 16 +
               4 * lhi) = o;
  }
  if (lhi == 0) {
    int idx = (b * NH + h) * TX + qbase + l15;
    m_ws[idx] = mrun;
    il_ws[idx] = il;
  }
}

// ---------------------------------------------------------------------------
// att_mean v8: R15's all-heads-staged structure with the spill removed.
// ALL 8 heads' K tiles staged upfront via global_load_lds (64KB LDS, 8 loads
// in flight, ONE drain barrier), then a BARRIER-FREE fully-unrolled head loop
// (LDS read-only after the stage barrier; compiler can hoist the small Q/m/il
// loads freely — no barrier fence). 2-state Q rotation (32 VGPR, not 48) and
// NO min-waves launch-bounds cap: R15's (512,4) forced VGPR=64 -> scratch
// spill (WRITE_SIZE 65->432 MB, +82 µs). LDS itself caps at 2 blocks/CU, so
// the cap bought nothing. Swizzle involution on gload SOURCE (rule #21).
// ---------------------------------------------------------------------------
__global__ __launch_bounds__(512) void att_mean_k(
    const unsigned short* __restrict__ Qw, const unsigned short* __restrict__ Kw,
    const float* __restrict__ m_ws, const float* __restrict__ il_ws,
    float* __restrict__ attm) {
  __shared__ __align__(16) unsigned short ktl[NH][64 * 64];  // 64KB, all heads

  const int tid = threadIdx.x;
  const int wid = tid >> 6, l = tid & 63, l15 = l & 15, lhi = l >> 4;
  const int qbase = blockIdx.x * 128 + wid * 16;
  const int keyb = blockIdx.y * 64;
  const int b = blockIdx.z;

  const unsigned short* Qb = Qw + (size_t)b * NH * TX * HD;
  const unsigned short* Kb = Kw + (size_t)b * NH * TC * HD;

  // swizzled read offsets (row&7 == l15&7)
  const int rs0 = (lhi ^ (l15 & 7)) << 3;
  const int rs1 = ((lhi ^ 4) ^ (l15 & 7)) << 3;

  // gload staging map: unit u = wid*64 + l -> row u>>3, slot u&7; LDS linear,
  // source col16 = slot ^ (row&7) (same involution the reads apply)
  const int srow = (wid * 64 + l) >> 3;
  const int sgc = ((l & 7) ^ (srow & 7)) * 8;

  bf16x8 aq0[2], aq1[2];
  f32x4 mm[2], ii[2];

  auto load_q = [&](int h, int p) {
    const unsigned short* qp =
        Qb + ((size_t)h * TX + qbase + l15) * HD + lhi * 8;
    aq0[p] = *(const bf16x8*)qp;
    aq1[p] = *(const bf16x8*)(qp + 32);
    mm[p] = *(const f32x4*)(m_ws + (size_t)(b * NH + h) * TX + qbase + 4 * lhi);
    ii[p] = *(const f32x4*)(il_ws + (size_t)(b * NH + h) * TX + qbase + 4 * lhi);
  };

  // stage ALL heads (8 gloads in flight), preload Q state 0 meanwhile
#pragma unroll
  for (int h = 0; h < NH; h++)
    gload_lds16(Kb + ((size_t)h * TC + keyb + srow) * HD + sgc,
                &ktl[h][wid * 512]);
  load_q(0, 0);
  __syncthreads();  // single drain: all K tiles resident

  f32x4 am[4];
#pragma unroll
  for (int kb = 0; kb < 4; kb++) am[kb] = zero4();

#pragma unroll
  for (int h = 0; h < NH; h++) {
    const int p = h & 1;
    if (h + 1 < NH) load_q(h + 1, p ^ 1);  // next head's Q/m/il in flight

#pragma unroll
    for (int kb = 0; kb < 4; kb++) {
      bf16x8 bk0 = *(const bf16x8*)&ktl[h][(kb * 16 + l15) * 64 + rs0];
      bf16x8 bk1 = *(const bf16x8*)&ktl[h][(kb * 16 + l15) * 64 + rs1];
      f32x4 a = zero4();
      a = mfma16(aq0[p], bk0, a);
      a = mfma16(aq1[p], bk1, a);
#pragma unroll
      for (int r = 0; r < 4; r++)
        am[kb][r] += exp2f(a[r] - mm[p][r]) * ii[p][r];
    }
  }

#pragma unroll
  for (int kb = 0; kb < 4; kb++)
#pragma unroll
    for (int r = 0; r < 4; r++) {
      int trow = qbase + 4 * lhi + r;
      attm[(size_t)(b * TX + trow) * TC + keyb + kb * 16 + l15] = am[kb][r] * 0.125f;
    }
}

// ---------------------------------------------------------------------------
extern "C" void kernel_launch(void* const* d_in, const int* in_sizes, int n_in,
                              void* d_out, int out_size, void* d_ws, size_t ws_size,
                              hipStream_t stream) {
  const float* x   = (const float*)d_in[0];
  const float* ctx = (const float*)d_in[1];
  const float* Wq  = (const float*)d_in[2];
  const float* bq  = (const float*)d_in[3];
  const float* Wk  = (const float*)d_in[4];
  const float* bk  = (const float*)d_in[5];
  const float* Wv  = (const float*)d_in[6];
  const float* bv  = (const float*)d_in[7];
  const float* Wo  = (const float*)d_in[8];
  const float* bo  = (const float*)d_in[9];

  float* y_out = (float*)d_out;                       // (B, Tx, C)
  float* attm  = y_out + (size_t)Bb * TX * CC;        // (B, Tx, Tc)

  // workspace layout (16B-aligned), ~53 MB total:
  unsigned short* q_ws = (unsigned short*)d_ws;                  // B*NH*TX*HD bf16
  unsigned short* k_ws = q_ws + (size_t)Bb * NH * TX * HD;       // B*NH*TC*HD bf16
  unsigned short* v_ws = k_ws + (size_t)Bb * NH * TC * HD;       // B*NH*TC*HD bf16 (V^T)
  float* m_ws  = (float*)(v_ws + (size_t)Bb * NH * TC * HD);     // B*NH*TX f32
  float* il_ws = m_ws + (size_t)Bb * NH * TX;                    // B*NH*TX f32
  unsigned short* y_pre = (unsigned short*)(il_ws + (size_t)Bb * NH * TX);  // B*TX*CC bf16
  unsigned short* wb = y_pre + (size_t)Bb * TX * CC;             // 4x CC*CC bf16
  unsigned short* wbq = wb, *wbk = wb + CC * CC, *wbv = wb + 2 * CC * CC,
                 *wbo = wb + 3 * CC * CC;

  // bf16 input overlays (consumed before their regions are overwritten):
  unsigned short* xb = k_ws;              // read by Q-GEMM, then kv_gemm overwrites
  unsigned short* cb = (unsigned short*)attm;  // read by kv_gemm, att_mean_k overwrites

  const int NX8 = Bb * TX * CC / 8, NC8 = Bb * TC * CC / 8, NW8 = CC * CC / 8;
  cvt_all<<<dim3(2048), 256, 0, stream>>>(x, xb, NX8, ctx, cb, NC8,
                                          Wq, wbq, NW8, Wk, wbk, NW8,
                                          Wv, wbv, NW8, Wo, wbo, NW8);

  // Q pre-scaled by log2(e)/sqrt(hd) so attention exp is bare v_exp_f32 (2^x)
  gemm128<0><<<dim3(CC / 128, (Bb * TX) / 128), 256, 0, stream>>>(
      xb, wbq, bq, q_ws, 10, 0.125f * LOG2E);
  kv_gemm128<<<dim3(CC / 128, (Bb * TC) / 128), 256, 0, stream>>>(
      cb, wbk, wbv, bk, bv, k_ws, v_ws);
  attn_fwd<<<dim3(TX / 128, NH, Bb), 512, 0, stream>>>(q_ws, k_ws, v_ws, y_pre, m_ws, il_ws);
  att_mean_k<<<dim3(TX / 128, TC / 64, Bb), 512, 0, stream>>>(q_ws, k_ws, m_ws, il_ws, attm);
  gemm128<1><<<dim3(CC / 128, (Bb * TX) / 128), 256, 0, stream>>>(
      y_pre, wbo, bo, y_out, 10, 1.0f);
}

// Round 18
// 205.530 us; speedup vs baseline: 1.0996x; 1.0996x over previous
//
#include <hip/hip_runtime.h>

#define DEVI __device__ __forceinline__

typedef short bf16x8 __attribute__((ext_vector_type(8)));
typedef short bf16x4 __attribute__((ext_vector_type(4)));
typedef float f32x4 __attribute__((ext_vector_type(4)));

constexpr int Bb = 8, TX = 1024, TC = 2048, CC = 512, NH = 8, HD = 64;
constexpr float LOG2E = 1.44269504f;

// fp32 -> bf16 round-to-nearest-even (values here are well-behaved, no NaN/Inf)
DEVI unsigned short f2bf(float f) {
  union { float f; unsigned u; } v; v.f = f;
  return (unsigned short)((v.u + 0x7FFFu + ((v.u >> 16) & 1u)) >> 16);
}

// packed f32x2 -> bf16x2 (low = lo, high = hi); no builtin on gfx950 (T12)
DEVI unsigned cvtpk(float lo, float hi) {
  unsigned r;
  asm("v_cvt_pk_bf16_f32 %0, %1, %2" : "=v"(r) : "v"(lo), "v"(hi));
  return r;
}

DEVI f32x4 mfma16(bf16x8 a, bf16x8 b, f32x4 c) {
  return __builtin_amdgcn_mfma_f32_16x16x32_bf16(a, b, c, 0, 0, 0);
}

DEVI f32x4 zero4() { f32x4 z = {0.f, 0.f, 0.f, 0.f}; return z; }

DEVI float max3f(float a, float b, float c) { return fmaxf(fmaxf(a, b), c); }

// async global->LDS, 16B per lane; LDS dest is wave-uniform base + lane*16,
// global source is per-lane (swizzled source = swizzled LDS layout, m173)
DEVI void gload_lds16(const unsigned short* g, unsigned short* l) {
  __builtin_amdgcn_global_load_lds(
      (const __attribute__((address_space(1))) void*)g,
      (__attribute__((address_space(3))) void*)l, 16, 0, 0);
}

// ---------------------------------------------------------------------------
// Fused fp32 -> bf16 convert for all 6 regions in ONE launch.
// ---------------------------------------------------------------------------
DEVI void cvt_region(const float* __restrict__ src,
                     unsigned short* __restrict__ dst, int n8, int i0, int stride) {
  for (int i = i0; i < n8; i += stride) {
    f32x4 a = *(const f32x4*)(src + (size_t)i * 8);
    f32x4 b = *(const f32x4*)(src + (size_t)i * 8 + 4);
    bf16x8 v;
#pragma unroll
    for (int j = 0; j < 4; j++) {
      v[j] = (short)f2bf(a[j]);
      v[j + 4] = (short)f2bf(b[j]);
    }
    *(bf16x8*)(dst + (size_t)i * 8) = v;
  }
}

__global__ __launch_bounds__(256) void cvt_all(
    const float* __restrict__ s0, unsigned short* __restrict__ d0, int n0,
    const float* __restrict__ s1, unsigned short* __restrict__ d1, int n1,
    const float* __restrict__ s2, unsigned short* __restrict__ d2, int n2,
    const float* __restrict__ s3, unsigned short* __restrict__ d3, int n3,
    const float* __restrict__ s4, unsigned short* __restrict__ d4, int n4,
    const float* __restrict__ s5, unsigned short* __restrict__ d5, int n5) {
  const int i0 = blockIdx.x * 256 + threadIdx.x;
  const int stride = gridDim.x * 256;
  cvt_region(s0, d0, n0, i0, stride);
  cvt_region(s1, d1, n1, i0, stride);
  cvt_region(s2, d2, n2, i0, stride);
  cvt_region(s3, d3, n3, i0, stride);
  cvt_region(s4, d4, n4, i0, stride);
  cvt_region(s5, d5, n5, i0, stride);
}

// ---------------------------------------------------------------------------
// 64x128-tile NT GEMM for the thin-M projections (Q-proj, O-proj): the 128^2
// tile left only 256 blocks = 1 block/CU (latency-starved). BM=64 doubles the
// grid to 512 blocks, LDS 24KB (many blocks/CU). 4 waves in 2x2: each wave
// 32(M)x64(N) = 2x4 MFMA frags. Same gload_lds staging + source-side swizzle
// (slot ^= (row>>1)&3) and same one-barrier/K-step schedule as gemm128.
// MODE 0: out bf16 permuted to (b,h,t,d).  MODE 1: out fp32 (r*512+c).
// ---------------------------------------------------------------------------
template <int MODE>
__global__ __launch_bounds__(256) void gemm64m(
    const unsigned short* __restrict__ A, const unsigned short* __restrict__ W,
    const float* __restrict__ bias, void* __restrict__ outp, int tlog2, float scale) {
  __shared__ __align__(16) unsigned short As[2][64 * 32];
  __shared__ __align__(16) unsigned short Bs[2][128 * 32];

  const int tid = threadIdx.x;
  const int wid = tid >> 6, l = tid & 63, l15 = l & 15, lhi = l >> 4;
  const int wm = wid >> 1, wn = wid & 1;
  const int mbase = blockIdx.y * 64, nbase = blockIdx.x * 128;

  f32x4 acc[2][4];
#pragma unroll
  for (int i = 0; i < 2; i++)
#pragma unroll
    for (int j = 0; j < 4; j++) acc[i][j] = zero4();

  auto stage = [&](int buf, int k0) {
    {  // A tile: 64 rows x 4 slots = 256 units, one per thread
      const int u = wid * 64 + l;
      const int row = u >> 2;
      const int gc = ((u & 3) ^ ((row >> 1) & 3)) * 8;
      gload_lds16(A + (size_t)(mbase + row) * CC + k0 + gc,
                  &As[buf][(wid * 64) * 8]);
    }
#pragma unroll
    for (int i = 0; i < 2; i++) {  // B tile: 128 rows x 4 slots = 512 units
      const int u = wid * 128 + i * 64 + l;
      const int row = u >> 2;
      const int gc = ((u & 3) ^ ((row >> 1) & 3)) * 8;
      gload_lds16(W + (size_t)(nbase + row) * CC + k0 + gc,
                  &Bs[buf][(wid * 128 + i * 64) * 8]);
    }
  };

  stage(0, 0);

  const int sA = (lhi ^ ((l15 >> 1) & 3)) << 3;

  constexpr int NK = CC / 32;
  for (int kt = 0; kt < NK; kt++) {
    const int cur = kt & 1;
    __syncthreads();
    if (kt + 1 < NK) stage(cur ^ 1, (kt + 1) * 32);

    bf16x8 af[2], bfr[4];
#pragma unroll
    for (int mi = 0; mi < 2; mi++)
      af[mi] = *(const bf16x8*)&As[cur][(wm * 32 + mi * 16 + l15) * 32 + sA];
#pragma unroll
    for (int ni = 0; ni < 4; ni++)
      bfr[ni] = *(const bf16x8*)&Bs[cur][(wn * 64 + ni * 16 + l15) * 32 + sA];
#pragma unroll
    for (int mi = 0; mi < 2; mi++)
#pragma unroll
      for (int ni = 0; ni < 4; ni++)
        acc[mi][ni] = mfma16(af[mi], bfr[ni], acc[mi][ni]);
  }

#pragma unroll
  for (int mi = 0; mi < 2; mi++)
#pragma unroll
    for (int ni = 0; ni < 4; ni++)
#pragma unroll
      for (int r = 0; r < 4; r++) {
        int grow = mbase + wm * 32 + mi * 16 + 4 * lhi + r;
        int gcol = nbase + wn * 64 + ni * 16 + l15;
        float val = (acc[mi][ni][r] + bias[gcol]) * scale;
        if (MODE == 0) {
          int T = 1 << tlog2;
          int bq = grow >> tlog2, tt = grow & (T - 1);
          int h = gcol >> 6, d = gcol & 63;
          size_t oidx = ((size_t)(bq * NH + h) * T + tt) * HD + d;
          ((unsigned short*)outp)[oidx] = f2bf(val);
        } else {
          ((float*)outp)[(size_t)grow * CC + gcol] = val;
        }
      }
}

// ---------------------------------------------------------------------------
// Fused K+V projection, 128x128 tile + global_load_lds: one A (ctx) tile
// feeds both Wk and Wv B-tiles (32 MFMA/K-step). K -> (b,h,t,d); V -> V^T.
// ---------------------------------------------------------------------------
__global__ __launch_bounds__(256, 2) void kv_gemm128(
    const unsigned short* __restrict__ A, const unsigned short* __restrict__ Wk,
    const unsigned short* __restrict__ Wv, const float* __restrict__ bk,
    const float* __restrict__ bv, unsigned short* __restrict__ k_out,
    unsigned short* __restrict__ v_out) {
  __shared__ __align__(16) unsigned short As[2][128 * 32];
  __shared__ __align__(16) unsigned short Bks[2][128 * 32];
  __shared__ __align__(16) unsigned short Bvs[2][128 * 32];

  const int tid = threadIdx.x;
  const int wid = tid >> 6, l = tid & 63, l15 = l & 15, lhi = l >> 4;
  const int wm = wid >> 1, wn = wid & 1;
  const int mbase = blockIdx.y * 128, nbase = blockIdx.x * 128;

  f32x4 acck[4][4], accv[4][4];
#pragma unroll
  for (int i = 0; i < 4; i++)
#pragma unroll
    for (int j = 0; j < 4; j++) { acck[i][j] = zero4(); accv[i][j] = zero4(); }

  auto stage = [&](int buf, int k0) {
#pragma unroll
    for (int i = 0; i < 2; i++) {
      const int u = wid * 128 + i * 64 + l;
      const int row = u >> 2;
      const int gc = ((u & 3) ^ ((row >> 1) & 3)) * 8;
      const int lo = (wid * 128 + i * 64) * 8;
      gload_lds16(A + (size_t)(mbase + row) * CC + k0 + gc, &As[buf][lo]);
      gload_lds16(Wk + (size_t)(nbase + row) * CC + k0 + gc, &Bks[buf][lo]);
      gload_lds16(Wv + (size_t)(nbase + row) * CC + k0 + gc, &Bvs[buf][lo]);
    }
  };

  stage(0, 0);

  const int sA = (lhi ^ ((l15 >> 1) & 3)) << 3;

  constexpr int NK = CC / 32;
  for (int kt = 0; kt < NK; kt++) {
    const int cur = kt & 1;
    __syncthreads();
    if (kt + 1 < NK) stage(cur ^ 1, (kt + 1) * 32);

    bf16x8 af[4], kf[4], vf[4];
#pragma unroll
    for (int mi = 0; mi < 4; mi++)
      af[mi] = *(const bf16x8*)&As[cur][(wm * 64 + mi * 16 + l15) * 32 + sA];
#pragma unroll
    for (int ni = 0; ni < 4; ni++) {
      kf[ni] = *(const bf16x8*)&Bks[cur][(wn * 64 + ni * 16 + l15) * 32 + sA];
      vf[ni] = *(const bf16x8*)&Bvs[cur][(wn * 64 + ni * 16 + l15) * 32 + sA];
    }
#pragma unroll
    for (int mi = 0; mi < 4; mi++)
#pragma unroll
      for (int ni = 0; ni < 4; ni++) {
        acck[mi][ni] = mfma16(af[mi], kf[ni], acck[mi][ni]);
        accv[mi][ni] = mfma16(af[mi], vf[ni], accv[mi][ni]);
      }
  }

#pragma unroll
  for (int mi = 0; mi < 4; mi++)
#pragma unroll
    for (int ni = 0; ni < 4; ni++)
#pragma unroll
      for (int r = 0; r < 4; r++) {
        int grow = mbase + wm * 64 + mi * 16 + 4 * lhi + r;
        int gcol = nbase + wn * 64 + ni * 16 + l15;
        int bq = grow >> 11, tt = grow & (TC - 1);
        int h = gcol >> 6, d = gcol & 63;
        float kv = acck[mi][ni][r] + bk[gcol];
        float vv = accv[mi][ni][r] + bv[gcol];
        k_out[((size_t)(bq * NH + h) * TC + tt) * HD + d] = f2bf(kv);
        v_out[((size_t)(bq * NH + h) * HD + d) * TC + tt] = f2bf(vv);
      }
}

// ---------------------------------------------------------------------------
// Flash attention fwd v9 (unchanged): 8 waves; swapped-QK^T in-register
// softmax; ones-MFMA row-sum; max3 tree; XOR-swizzled K/V LDS; exp2 softmax;
// defer-max; setprio on MFMA clusters; one barrier/iter.
// ---------------------------------------------------------------------------
__global__ __launch_bounds__(512) void attn_fwd(
    const unsigned short* __restrict__ Qw, const unsigned short* __restrict__ Kw,
    const unsigned short* __restrict__ Vtw, unsigned short* __restrict__ y_pre,
    float* __restrict__ m_ws, float* __restrict__ il_ws) {
  __shared__ __align__(16) unsigned short ktl[2][64 * 64];  // [buf][key][d] swz
  __shared__ __align__(16) unsigned short vtl[2][64 * 64];  // [buf][d][key] swz

  const int tid = threadIdx.x;
  const int wid = tid >> 6, l = tid & 63, l15 = l & 15, lhi = l >> 4;
  const int qg = blockIdx.x, h = blockIdx.y, b = blockIdx.z;
  const int qbase = qg * 128 + wid * 16;

  const unsigned short* Qh = Qw + (size_t)(b * NH + h) * TX * HD;
  const unsigned short* Kh = Kw + (size_t)(b * NH + h) * TC * HD;
  const unsigned short* Vt = Vtw + (size_t)(b * NH + h) * TC * HD;  // (d, t)

  bf16x8 aq0 = *(const bf16x8*)(Qh + (size_t)(qbase + l15) * HD + lhi * 8);
  bf16x8 aq1 = *(const bf16x8*)(Qh + (size_t)(qbase + l15) * HD + 32 + lhi * 8);

  bf16x8 ones;
#pragma unroll
  for (int j = 0; j < 8; j++) ones[j] = (short)0x3F80;  // bf16 1.0

  f32x4 accy[4];
#pragma unroll
  for (int db = 0; db < 4; db++) accy[db] = zero4();
  f32x4 accl = zero4();  // P-row-sum accumulator (ones-MFMA)
  float mrun = -1e30f;

  const int sl0 = l15 + ((lhi & 1) << 5);
  const int sl1 = sl0 + 16;
  const bool sel = ((lhi >> 1) & 1) != 0;

  const int rs0 = (lhi ^ (l15 & 7)) << 3;
  const int rs1 = ((lhi ^ 4) ^ (l15 & 7)) << 3;

  const int sr = tid >> 3;
  const int ssw = ((tid & 7) ^ (sr & 7)) << 3;
  const int sc0 = (tid & 7) * 8;

  bf16x8 kr = *(const bf16x8*)(Kh + (size_t)sr * HD + sc0);
  bf16x8 vp = *(const bf16x8*)(Vt + (size_t)sr * TC + sc0);
  *(bf16x8*)&ktl[0][sr * 64 + ssw] = kr;
  *(bf16x8*)&vtl[0][sr * 64 + ssw] = vp;
  __syncthreads();

  constexpr int NT = TC / 64;
  for (int kt = 0; kt < NT; kt++) {
    const int cur = kt & 1;

    if (kt + 1 < NT) {
      const int keyn = (kt + 1) * 64;
      kr = *(const bf16x8*)(Kh + (size_t)(keyn + sr) * HD + sc0);
      vp = *(const bf16x8*)(Vt + (size_t)sr * TC + keyn + sc0);
    }

    f32x4 s[4];
    __builtin_amdgcn_s_setprio(1);
#pragma unroll
    for (int kb = 0; kb < 4; kb++) {
      bf16x8 bk0 = *(const bf16x8*)&ktl[cur][(kb * 16 + l15) * 64 + rs0];
      bf16x8 bk1 = *(const bf16x8*)&ktl[cur][(kb * 16 + l15) * 64 + rs1];
      f32x4 a = zero4();
      a = mfma16(bk0, aq0, a);
      a = mfma16(bk1, aq1, a);
      s[kb] = a;
    }
    __builtin_amdgcn_s_setprio(0);

    float t0 = max3f(s[0][0], s[0][1], s[0][2]);
    float t1 = max3f(s[0][3], s[1][0], s[1][1]);
    float t2 = max3f(s[1][2], s[1][3], s[2][0]);
    float t3 = max3f(s[2][1], s[2][2], s[2][3]);
    float t4 = max3f(s[3][0], s[3][1], s[3][2]);
    float mx = fmaxf(max3f(t0, t1, t2), max3f(t3, t4, s[3][3]));
    mx = fmaxf(mx, __shfl_xor(mx, 16));
    mx = fmaxf(mx, __shfl_xor(mx, 32));

    if (__any(mx - mrun > 7.0f)) {
      float mn = fmaxf(mrun, mx);
      float sc = exp2f(mrun - mn);
      mrun = mn;
#pragma unroll
      for (int r = 0; r < 4; r++) accl[r] *= sc;
#pragma unroll
      for (int db = 0; db < 4; db++)
#pragma unroll
        for (int r = 0; r < 4; r++) accy[db][r] *= sc;
    }

    float p[4][4];
#pragma unroll
    for (int kb = 0; kb < 4; kb++)
#pragma unroll
      for (int r = 0; r < 4; r++) p[kb][r] = exp2f(s[kb][r] - mrun);

    unsigned pkw[4][2];
#pragma unroll
    for (int kb = 0; kb < 4; kb++) {
      pkw[kb][0] = cvtpk(p[kb][0], p[kb][1]);
      pkw[kb][1] = cvtpk(p[kb][2], p[kb][3]);
    }
    unsigned a00 = (unsigned)__shfl((int)pkw[0][0], sl0);
    unsigned a01 = (unsigned)__shfl((int)pkw[0][1], sl0);
    unsigned a10 = (unsigned)__shfl((int)pkw[1][0], sl0);
    unsigned a11 = (unsigned)__shfl((int)pkw[1][1], sl0);
    unsigned c00 = (unsigned)__shfl((int)pkw[0][0], sl1);
    unsigned c01 = (unsigned)__shfl((int)pkw[0][1], sl1);
    unsigned c10 = (unsigned)__shfl((int)pkw[1][0], sl1);
    unsigned c11 = (unsigned)__shfl((int)pkw[1][1], sl1);
    unsigned e00 = (unsigned)__shfl((int)pkw[2][0], sl0);
    unsigned e01 = (unsigned)__shfl((int)pkw[2][1], sl0);
    unsigned e10 = (unsigned)__shfl((int)pkw[3][0], sl0);
    unsigned e11 = (unsigned)__shfl((int)pkw[3][1], sl0);
    unsigned g00 = (unsigned)__shfl((int)pkw[2][0], sl1);
    unsigned g01 = (unsigned)__shfl((int)pkw[2][1], sl1);
    unsigned g10 = (unsigned)__shfl((int)pkw[3][0], sl1);
    unsigned g11 = (unsigned)__shfl((int)pkw[3][1], sl1);
    union { unsigned u[4]; bf16x8 v; } B0, B1;
    B0.u[0] = sel ? a10 : a00;
    B0.u[1] = sel ? a11 : a01;
    B0.u[2] = sel ? c10 : c00;
    B0.u[3] = sel ? c11 : c01;
    B1.u[0] = sel ? e10 : e00;
    B1.u[1] = sel ? e11 : e01;
    B1.u[2] = sel ? g10 : g00;
    B1.u[3] = sel ? g11 : g01;

    __builtin_amdgcn_s_setprio(1);
#pragma unroll
    for (int db = 0; db < 4; db++) {
      bf16x8 bv0 = *(const bf16x8*)&vtl[cur][(db * 16 + l15) * 64 + rs0];
      bf16x8 bv1 = *(const bf16x8*)&vtl[cur][(db * 16 + l15) * 64 + rs1];
      accy[db] = mfma16(bv0, B0.v, accy[db]);
      accy[db] = mfma16(bv1, B1.v, accy[db]);
    }
    accl = mfma16(ones, B0.v, accl);
    accl = mfma16(ones, B1.v, accl);
    __builtin_amdgcn_s_setprio(0);

    if (kt + 1 < NT) {
      const int nxt = cur ^ 1;
      *(bf16x8*)&ktl[nxt][sr * 64 + ssw] = kr;
      *(bf16x8*)&vtl[nxt][sr * 64 + ssw] = vp;
    }
    __syncthreads();
  }

  const float il = 1.f / accl[0];

#pragma unroll
  for (int db = 0; db < 4; db++) {
    bf16x4 o;
#pragma unroll
    for (int r = 0; r < 4; r++) o[r] = (short)f2bf(accy[db][r] * il);
    *(bf16x4*)(y_pre + (size_t)(b * TX + qbase + l15) * CC + h * HD + db * 16 +
               4 * lhi) = o;
  }
  if (lhi == 0) {
    int idx = (b * NH + h) * TX + qbase + l15;
    m_ws[idx] = mrun;
    il_ws[idx] = il;
  }
}

// ---------------------------------------------------------------------------
// att_mean v6 (the proven keeper — v7/v8 all-heads-staged variants lost to
// spill (R15) and occupancy (R17)). 8 waves / 512 threads = 128 q-rows x 64
// keys; per-head K tile staged in XOR-swizzled LDS (double-buffered, prefetch
// top / commit bottom, one barrier per head); p = 2^(s-m) * (1/l).
// ---------------------------------------------------------------------------
__global__ __launch_bounds__(512) void att_mean_k(
    const unsigned short* __restrict__ Qw, const unsigned short* __restrict__ Kw,
    const float* __restrict__ m_ws, const float* __restrict__ il_ws,
    float* __restrict__ attm) {
  __shared__ __align__(16) unsigned short ktl[2][64 * 64];  // [buf][key][d] swz

  const int tid = threadIdx.x;
  const int wid = tid >> 6, l = tid & 63, l15 = l & 15, lhi = l >> 4;
  const int qbase = blockIdx.x * 128 + wid * 16;  // x = q tile (fastest)
  const int keyb = blockIdx.y * 64;               // y = key tile
  const int b = blockIdx.z;

  const unsigned short* Qb = Qw + (size_t)b * NH * TX * HD;
  const unsigned short* Kb = Kw + (size_t)b * NH * TC * HD;

  const int rs0 = (lhi ^ (l15 & 7)) << 3;
  const int rs1 = ((lhi ^ 4) ^ (l15 & 7)) << 3;

  const int sr = tid >> 3;
  const int ssw = ((tid & 7) ^ (sr & 7)) << 3;
  const int sc0 = (tid & 7) * 8;

  bf16x8 aq0[2], aq1[2];
  f32x4 mm[2], ii[2];

  auto load_q = [&](int h, int p) {
    const unsigned short* qp =
        Qb + ((size_t)h * TX + qbase + l15) * HD + lhi * 8;
    aq0[p] = *(const bf16x8*)qp;
    aq1[p] = *(const bf16x8*)(qp + 32);
    mm[p] = *(const f32x4*)(m_ws + (size_t)(b * NH + h) * TX + qbase + 4 * lhi);
    ii[p] = *(const f32x4*)(il_ws + (size_t)(b * NH + h) * TX + qbase + 4 * lhi);
  };

  bf16x8 kr = *(const bf16x8*)(Kb + ((size_t)keyb + sr) * HD + sc0);
  load_q(0, 0);
  *(bf16x8*)&ktl[0][sr * 64 + ssw] = kr;
  __syncthreads();

  f32x4 am[4];
#pragma unroll
  for (int kb = 0; kb < 4; kb++) am[kb] = zero4();

#pragma unroll
  for (int h = 0; h < NH; h++) {
    const int cur = h & 1;

    if (h + 1 < NH) {
      kr = *(const bf16x8*)(Kb + ((size_t)(h + 1) * TC + keyb + sr) * HD + sc0);
      load_q(h + 1, cur ^ 1);
    }

#pragma unroll
    for (int kb = 0; kb < 4; kb++) {
      bf16x8 bk0 = *(const bf16x8*)&ktl[cur][(kb * 16 + l15) * 64 + rs0];
      bf16x8 bk1 = *(const bf16x8*)&ktl[cur][(kb * 16 + l15) * 64 + rs1];
      f32x4 a = zero4();
      a = mfma16(aq0[cur], bk0, a);
      a = mfma16(aq1[cur], bk1, a);
#pragma unroll
      for (int r = 0; r < 4; r++)
        am[kb][r] += exp2f(a[r] - mm[cur][r]) * ii[cur][r];
    }

    if (h + 1 < NH) {
      const int nxt = cur ^ 1;
      *(bf16x8*)&ktl[nxt][sr * 64 + ssw] = kr;
    }
    __syncthreads();
  }

#pragma unroll
  for (int kb = 0; kb < 4; kb++)
#pragma unroll
    for (int r = 0; r < 4; r++) {
      int trow = qbase + 4 * lhi + r;
      attm[(size_t)(b * TX + trow) * TC + keyb + kb * 16 + l15] = am[kb][r] * 0.125f;
    }
}

// ---------------------------------------------------------------------------
extern "C" void kernel_launch(void* const* d_in, const int* in_sizes, int n_in,
                              void* d_out, int out_size, void* d_ws, size_t ws_size,
                              hipStream_t stream) {
  const float* x   = (const float*)d_in[0];
  const float* ctx = (const float*)d_in[1];
  const float* Wq  = (const float*)d_in[2];
  const float* bq  = (const float*)d_in[3];
  const float* Wk  = (const float*)d_in[4];
  const float* bk  = (const float*)d_in[5];
  const float* Wv  = (const float*)d_in[6];
  const float* bv  = (const float*)d_in[7];
  const float* Wo  = (const float*)d_in[8];
  const float* bo  = (const float*)d_in[9];

  float* y_out = (float*)d_out;                       // (B, Tx, C)
  float* attm  = y_out + (size_t)Bb * TX * CC;        // (B, Tx, Tc)

  // workspace layout (16B-aligned), ~53 MB total:
  unsigned short* q_ws = (unsigned short*)d_ws;                  // B*NH*TX*HD bf16
  unsigned short* k_ws = q_ws + (size_t)Bb * NH * TX * HD;       // B*NH*TC*HD bf16
  unsigned short* v_ws = k_ws + (size_t)Bb * NH * TC * HD;       // B*NH*TC*HD bf16 (V^T)
  float* m_ws  = (float*)(v_ws + (size_t)Bb * NH * TC * HD);     // B*NH*TX f32
  float* il_ws = m_ws + (size_t)Bb * NH * TX;                    // B*NH*TX f32
  unsigned short* y_pre = (unsigned short*)(il_ws + (size_t)Bb * NH * TX);  // B*TX*CC bf16
  unsigned short* wb = y_pre + (size_t)Bb * TX * CC;             // 4x CC*CC bf16
  unsigned short* wbq = wb, *wbk = wb + CC * CC, *wbv = wb + 2 * CC * CC,
                 *wbo = wb + 3 * CC * CC;

  // bf16 input overlays (consumed before their regions are overwritten):
  unsigned short* xb = k_ws;              // read by Q-GEMM, then kv_gemm overwrites
  unsigned short* cb = (unsigned short*)attm;  // read by kv_gemm, att_mean_k overwrites

  const int NX8 = Bb * TX * CC / 8, NC8 = Bb * TC * CC / 8, NW8 = CC * CC / 8;
  cvt_all<<<dim3(2048), 256, 0, stream>>>(x, xb, NX8, ctx, cb, NC8,
                                          Wq, wbq, NW8, Wk, wbk, NW8,
                                          Wv, wbv, NW8, Wo, wbo, NW8);

  // Q pre-scaled by log2(e)/sqrt(hd) so attention exp is bare v_exp_f32 (2^x)
  gemm64m<0><<<dim3(CC / 128, (Bb * TX) / 64), 256, 0, stream>>>(
      xb, wbq, bq, q_ws, 10, 0.125f * LOG2E);
  kv_gemm128<<<dim3(CC / 128, (Bb * TC) / 128), 256, 0, stream>>>(
      cb, wbk, wbv, bk, bv, k_ws, v_ws);
  attn_fwd<<<dim3(TX / 128, NH, Bb), 512, 0, stream>>>(q_ws, k_ws, v_ws, y_pre, m_ws, il_ws);
  att_mean_k<<<dim3(TX / 128, TC / 64, Bb), 512, 0, stream>>>(q_ws, k_ws, m_ws, il_ws, attm);
  gemm64m<1><<<dim3(CC / 128, (Bb * TX) / 64), 256, 0, stream>>>(
      y_pre, wbo, bo, y_out, 10, 1.0f);
}

// Round 19
// 204.583 us; speedup vs baseline: 1.1047x; 1.0046x over previous
//
#include <hip/hip_runtime.h>

#define DEVI __device__ __forceinline__

typedef short bf16x8 __attribute__((ext_vector_type(8)));
typedef short bf16x4 __attribute__((ext_vector_type(4)));
typedef float f32x4 __attribute__((ext_vector_type(4)));

constexpr int Bb = 8, TX = 1024, TC = 2048, CC = 512, NH = 8, HD = 64;
constexpr float LOG2E = 1.44269504f;

// fp32 -> bf16 round-to-nearest-even (values here are well-behaved, no NaN/Inf)
DEVI unsigned short f2bf(float f) {
  union { float f; unsigned u; } v; v.f = f;
  return (unsigned short)((v.u + 0x7FFFu + ((v.u >> 16) & 1u)) >> 16);
}

// packed f32x2 -> bf16x2 (low = lo, high = hi); no builtin on gfx950 (T12)
DEVI unsigned cvtpk(float lo, float hi) {
  unsigned r;
  asm("v_cvt_pk_bf16_f32 %0, %1, %2" : "=v"(r) : "v"(lo), "v"(hi));
  return r;
}

DEVI f32x4 mfma16(bf16x8 a, bf16x8 b, f32x4 c) {
  return __builtin_amdgcn_mfma_f32_16x16x32_bf16(a, b, c, 0, 0, 0);
}

DEVI f32x4 zero4() { f32x4 z = {0.f, 0.f, 0.f, 0.f}; return z; }

DEVI float max3f(float a, float b, float c) { return fmaxf(fmaxf(a, b), c); }

// async global->LDS, 16B per lane; LDS dest is wave-uniform base + lane*16,
// global source is per-lane (swizzled source = swizzled LDS layout, m173)
DEVI void gload_lds16(const unsigned short* g, unsigned short* l) {
  __builtin_amdgcn_global_load_lds(
      (const __attribute__((address_space(1))) void*)g,
      (__attribute__((address_space(3))) void*)l, 16, 0, 0);
}

// ---------------------------------------------------------------------------
// Fused fp32 -> bf16 convert for all 6 regions in ONE launch.
// ---------------------------------------------------------------------------
DEVI void cvt_region(const float* __restrict__ src,
                     unsigned short* __restrict__ dst, int n8, int i0, int stride) {
  for (int i = i0; i < n8; i += stride) {
    f32x4 a = *(const f32x4*)(src + (size_t)i * 8);
    f32x4 b = *(const f32x4*)(src + (size_t)i * 8 + 4);
    bf16x8 v;
#pragma unroll
    for (int j = 0; j < 4; j++) {
      v[j] = (short)f2bf(a[j]);
      v[j + 4] = (short)f2bf(b[j]);
    }
    *(bf16x8*)(dst + (size_t)i * 8) = v;
  }
}

__global__ __launch_bounds__(256) void cvt_all(
    const float* __restrict__ s0, unsigned short* __restrict__ d0, int n0,
    const float* __restrict__ s1, unsigned short* __restrict__ d1, int n1,
    const float* __restrict__ s2, unsigned short* __restrict__ d2, int n2,
    const float* __restrict__ s3, unsigned short* __restrict__ d3, int n3,
    const float* __restrict__ s4, unsigned short* __restrict__ d4, int n4,
    const float* __restrict__ s5, unsigned short* __restrict__ d5, int n5) {
  const int i0 = blockIdx.x * 256 + threadIdx.x;
  const int stride = gridDim.x * 256;
  cvt_region(s0, d0, n0, i0, stride);
  cvt_region(s1, d1, n1, i0, stride);
  cvt_region(s2, d2, n2, i0, stride);
  cvt_region(s3, d3, n3, i0, stride);
  cvt_region(s4, d4, n4, i0, stride);
  cvt_region(s5, d5, n5, i0, stride);
}

// ---------------------------------------------------------------------------
// 64x128-tile NT GEMM for the thin-M projections (Q-proj, O-proj).
// Same gload_lds staging + source-side swizzle and one-barrier/K-step
// schedule as gemm128; BM=64 doubles the grid (512 blocks, latency hiding).
// MODE 0: out bf16 permuted to (b,h,t,d).  MODE 1: out fp32 (r*512+c).
// ---------------------------------------------------------------------------
template <int MODE>
__global__ __launch_bounds__(256) void gemm64m(
    const unsigned short* __restrict__ A, const unsigned short* __restrict__ W,
    const float* __restrict__ bias, void* __restrict__ outp, int tlog2, float scale) {
  __shared__ __align__(16) unsigned short As[2][64 * 32];
  __shared__ __align__(16) unsigned short Bs[2][128 * 32];

  const int tid = threadIdx.x;
  const int wid = tid >> 6, l = tid & 63, l15 = l & 15, lhi = l >> 4;
  const int wm = wid >> 1, wn = wid & 1;
  const int mbase = blockIdx.y * 64, nbase = blockIdx.x * 128;

  f32x4 acc[2][4];
#pragma unroll
  for (int i = 0; i < 2; i++)
#pragma unroll
    for (int j = 0; j < 4; j++) acc[i][j] = zero4();

  auto stage = [&](int buf, int k0) {
    {  // A tile: 64 rows x 4 slots = 256 units, one per thread
      const int u = wid * 64 + l;
      const int row = u >> 2;
      const int gc = ((u & 3) ^ ((row >> 1) & 3)) * 8;
      gload_lds16(A + (size_t)(mbase + row) * CC + k0 + gc,
                  &As[buf][(wid * 64) * 8]);
    }
#pragma unroll
    for (int i = 0; i < 2; i++) {  // B tile: 128 rows x 4 slots = 512 units
      const int u = wid * 128 + i * 64 + l;
      const int row = u >> 2;
      const int gc = ((u & 3) ^ ((row >> 1) & 3)) * 8;
      gload_lds16(W + (size_t)(nbase + row) * CC + k0 + gc,
                  &Bs[buf][(wid * 128 + i * 64) * 8]);
    }
  };

  stage(0, 0);

  const int sA = (lhi ^ ((l15 >> 1) & 3)) << 3;

  constexpr int NK = CC / 32;
  for (int kt = 0; kt < NK; kt++) {
    const int cur = kt & 1;
    __syncthreads();
    if (kt + 1 < NK) stage(cur ^ 1, (kt + 1) * 32);

    bf16x8 af[2], bfr[4];
#pragma unroll
    for (int mi = 0; mi < 2; mi++)
      af[mi] = *(const bf16x8*)&As[cur][(wm * 32 + mi * 16 + l15) * 32 + sA];
#pragma unroll
    for (int ni = 0; ni < 4; ni++)
      bfr[ni] = *(const bf16x8*)&Bs[cur][(wn * 64 + ni * 16 + l15) * 32 + sA];
#pragma unroll
    for (int mi = 0; mi < 2; mi++)
#pragma unroll
      for (int ni = 0; ni < 4; ni++)
        acc[mi][ni] = mfma16(af[mi], bfr[ni], acc[mi][ni]);
  }

#pragma unroll
  for (int mi = 0; mi < 2; mi++)
#pragma unroll
    for (int ni = 0; ni < 4; ni++)
#pragma unroll
      for (int r = 0; r < 4; r++) {
        int grow = mbase + wm * 32 + mi * 16 + 4 * lhi + r;
        int gcol = nbase + wn * 64 + ni * 16 + l15;
        float val = (acc[mi][ni][r] + bias[gcol]) * scale;
        if (MODE == 0) {
          int T = 1 << tlog2;
          int bq = grow >> tlog2, tt = grow & (T - 1);
          int h = gcol >> 6, d = gcol & 63;
          size_t oidx = ((size_t)(bq * NH + h) * T + tt) * HD + d;
          ((unsigned short*)outp)[oidx] = f2bf(val);
        } else {
          ((float*)outp)[(size_t)grow * CC + gcol] = val;
        }
      }
}

// ---------------------------------------------------------------------------
// Fused K+V projection, 128x128 tile + global_load_lds: one A (ctx) tile
// feeds both Wk and Wv B-tiles (32 MFMA/K-step). K -> (b,h,t,d); V -> V^T.
// ---------------------------------------------------------------------------
__global__ __launch_bounds__(256, 2) void kv_gemm128(
    const unsigned short* __restrict__ A, const unsigned short* __restrict__ Wk,
    const unsigned short* __restrict__ Wv, const float* __restrict__ bk,
    const float* __restrict__ bv, unsigned short* __restrict__ k_out,
    unsigned short* __restrict__ v_out) {
  __shared__ __align__(16) unsigned short As[2][128 * 32];
  __shared__ __align__(16) unsigned short Bks[2][128 * 32];
  __shared__ __align__(16) unsigned short Bvs[2][128 * 32];

  const int tid = threadIdx.x;
  const int wid = tid >> 6, l = tid & 63, l15 = l & 15, lhi = l >> 4;
  const int wm = wid >> 1, wn = wid & 1;
  const int mbase = blockIdx.y * 128, nbase = blockIdx.x * 128;

  f32x4 acck[4][4], accv[4][4];
#pragma unroll
  for (int i = 0; i < 4; i++)
#pragma unroll
    for (int j = 0; j < 4; j++) { acck[i][j] = zero4(); accv[i][j] = zero4(); }

  auto stage = [&](int buf, int k0) {
#pragma unroll
    for (int i = 0; i < 2; i++) {
      const int u = wid * 128 + i * 64 + l;
      const int row = u >> 2;
      const int gc = ((u & 3) ^ ((row >> 1) & 3)) * 8;
      const int lo = (wid * 128 + i * 64) * 8;
      gload_lds16(A + (size_t)(mbase + row) * CC + k0 + gc, &As[buf][lo]);
      gload_lds16(Wk + (size_t)(nbase + row) * CC + k0 + gc, &Bks[buf][lo]);
      gload_lds16(Wv + (size_t)(nbase + row) * CC + k0 + gc, &Bvs[buf][lo]);
    }
  };

  stage(0, 0);

  const int sA = (lhi ^ ((l15 >> 1) & 3)) << 3;

  constexpr int NK = CC / 32;
  for (int kt = 0; kt < NK; kt++) {
    const int cur = kt & 1;
    __syncthreads();
    if (kt + 1 < NK) stage(cur ^ 1, (kt + 1) * 32);

    bf16x8 af[4], kf[4], vf[4];
#pragma unroll
    for (int mi = 0; mi < 4; mi++)
      af[mi] = *(const bf16x8*)&As[cur][(wm * 64 + mi * 16 + l15) * 32 + sA];
#pragma unroll
    for (int ni = 0; ni < 4; ni++) {
      kf[ni] = *(const bf16x8*)&Bks[cur][(wn * 64 + ni * 16 + l15) * 32 + sA];
      vf[ni] = *(const bf16x8*)&Bvs[cur][(wn * 64 + ni * 16 + l15) * 32 + sA];
    }
#pragma unroll
    for (int mi = 0; mi < 4; mi++)
#pragma unroll
      for (int ni = 0; ni < 4; ni++) {
        acck[mi][ni] = mfma16(af[mi], kf[ni], acck[mi][ni]);
        accv[mi][ni] = mfma16(af[mi], vf[ni], accv[mi][ni]);
      }
  }

#pragma unroll
  for (int mi = 0; mi < 4; mi++)
#pragma unroll
    for (int ni = 0; ni < 4; ni++)
#pragma unroll
      for (int r = 0; r < 4; r++) {
        int grow = mbase + wm * 64 + mi * 16 + 4 * lhi + r;
        int gcol = nbase + wn * 64 + ni * 16 + l15;
        int bq = grow >> 11, tt = grow & (TC - 1);
        int h = gcol >> 6, d = gcol & 63;
        float kv = acck[mi][ni][r] + bk[gcol];
        float vv = accv[mi][ni][r] + bv[gcol];
        k_out[((size_t)(bq * NH + h) * TC + tt) * HD + d] = f2bf(kv);
        v_out[((size_t)(bq * NH + h) * HD + d) * TC + tt] = f2bf(vv);
      }
}

// ---------------------------------------------------------------------------
// Flash attention fwd v10 — v9 + XCD-aware block swizzle (T1). The default
// x-fastest mapping put the 8 qg-blocks sharing one (b,h)'s K/V on 8
// DIFFERENT XCDs (XCD = p%8 = qg): each XCD streamed 64 distinct (b,h) K/V
// panels (64 MB) through its 4 MB L2 -> FETCH 135 MB vs 42 MB cold. Decoding
// (qg,h,b) as qg=p>>6, h=(p>>3)&7, b=p&7 makes XCD = b: all of batch b's
// blocks co-resident on one XCD (working set ~10 MB). Bijective (512 = 8x64).
// Rest unchanged: 8 waves; swapped-QK^T in-register softmax; ones-MFMA
// row-sum; max3 tree; XOR-swizzled K/V LDS; exp2; defer-max; setprio.
// ---------------------------------------------------------------------------
__global__ __launch_bounds__(512) void attn_fwd(
    const unsigned short* __restrict__ Qw, const unsigned short* __restrict__ Kw,
    const unsigned short* __restrict__ Vtw, unsigned short* __restrict__ y_pre,
    float* __restrict__ m_ws, float* __restrict__ il_ws) {
  __shared__ __align__(16) unsigned short ktl[2][64 * 64];  // [buf][key][d] swz
  __shared__ __align__(16) unsigned short vtl[2][64 * 64];  // [buf][d][key] swz

  const int tid = threadIdx.x;
  const int wid = tid >> 6, l = tid & 63, l15 = l & 15, lhi = l >> 4;
  // XCD swizzle: linear id -> (qg,h,b) with XCD = p%8 = b
  const int p = blockIdx.x + (TX / 128) * (blockIdx.y + NH * blockIdx.z);
  const int qg = p >> 6, h = (p >> 3) & 7, b = p & 7;
  const int qbase = qg * 128 + wid * 16;

  const unsigned short* Qh = Qw + (size_t)(b * NH + h) * TX * HD;
  const unsigned short* Kh = Kw + (size_t)(b * NH + h) * TC * HD;
  const unsigned short* Vt = Vtw + (size_t)(b * NH + h) * TC * HD;  // (d, t)

  bf16x8 aq0 = *(const bf16x8*)(Qh + (size_t)(qbase + l15) * HD + lhi * 8);
  bf16x8 aq1 = *(const bf16x8*)(Qh + (size_t)(qbase + l15) * HD + 32 + lhi * 8);

  bf16x8 ones;
#pragma unroll
  for (int j = 0; j < 8; j++) ones[j] = (short)0x3F80;  // bf16 1.0

  f32x4 accy[4];
#pragma unroll
  for (int db = 0; db < 4; db++) accy[db] = zero4();
  f32x4 accl = zero4();  // P-row-sum accumulator (ones-MFMA)
  float mrun = -1e30f;

  const int sl0 = l15 + ((lhi & 1) << 5);
  const int sl1 = sl0 + 16;
  const bool sel = ((lhi >> 1) & 1) != 0;

  const int rs0 = (lhi ^ (l15 & 7)) << 3;
  const int rs1 = ((lhi ^ 4) ^ (l15 & 7)) << 3;

  const int sr = tid >> 3;
  const int ssw = ((tid & 7) ^ (sr & 7)) << 3;
  const int sc0 = (tid & 7) * 8;

  bf16x8 kr = *(const bf16x8*)(Kh + (size_t)sr * HD + sc0);
  bf16x8 vp = *(const bf16x8*)(Vt + (size_t)sr * TC + sc0);
  *(bf16x8*)&ktl[0][sr * 64 + ssw] = kr;
  *(bf16x8*)&vtl[0][sr * 64 + ssw] = vp;
  __syncthreads();

  constexpr int NT = TC / 64;
  for (int kt = 0; kt < NT; kt++) {
    const int cur = kt & 1;

    if (kt + 1 < NT) {
      const int keyn = (kt + 1) * 64;
      kr = *(const bf16x8*)(Kh + (size_t)(keyn + sr) * HD + sc0);
      vp = *(const bf16x8*)(Vt + (size_t)sr * TC + keyn + sc0);
    }

    f32x4 s[4];
    __builtin_amdgcn_s_setprio(1);
#pragma unroll
    for (int kb = 0; kb < 4; kb++) {
      bf16x8 bk0 = *(const bf16x8*)&ktl[cur][(kb * 16 + l15) * 64 + rs0];
      bf16x8 bk1 = *(const bf16x8*)&ktl[cur][(kb * 16 + l15) * 64 + rs1];
      f32x4 a = zero4();
      a = mfma16(bk0, aq0, a);
      a = mfma16(bk1, aq1, a);
      s[kb] = a;
    }
    __builtin_amdgcn_s_setprio(0);

    float t0 = max3f(s[0][0], s[0][1], s[0][2]);
    float t1 = max3f(s[0][3], s[1][0], s[1][1]);
    float t2 = max3f(s[1][2], s[1][3], s[2][0]);
    float t3 = max3f(s[2][1], s[2][2], s[2][3]);
    float t4 = max3f(s[3][0], s[3][1], s[3][2]);
    float mx = fmaxf(max3f(t0, t1, t2), max3f(t3, t4, s[3][3]));
    mx = fmaxf(mx, __shfl_xor(mx, 16));
    mx = fmaxf(mx, __shfl_xor(mx, 32));

    if (__any(mx - mrun > 7.0f)) {
      float mn = fmaxf(mrun, mx);
      float sc = exp2f(mrun - mn);
      mrun = mn;
#pragma unroll
      for (int r = 0; r < 4; r++) accl[r] *= sc;
#pragma unroll
      for (int db = 0; db < 4; db++)
#pragma unroll
        for (int r = 0; r < 4; r++) accy[db][r] *= sc;
    }

    float p4[4][4];
#pragma unroll
    for (int kb = 0; kb < 4; kb++)
#pragma unroll
      for (int r = 0; r < 4; r++) p4[kb][r] = exp2f(s[kb][r] - mrun);

    unsigned pkw[4][2];
#pragma unroll
    for (int kb = 0; kb < 4; kb++) {
      pkw[kb][0] = cvtpk(p4[kb][0], p4[kb][1]);
      pkw[kb][1] = cvtpk(p4[kb][2], p4[kb][3]);
    }
    unsigned a00 = (unsigned)__shfl((int)pkw[0][0], sl0);
    unsigned a01 = (unsigned)__shfl((int)pkw[0][1], sl0);
    unsigned a10 = (unsigned)__shfl((int)pkw[1][0], sl0);
    unsigned a11 = (unsigned)__shfl((int)pkw[1][1], sl0);
    unsigned c00 = (unsigned)__shfl((int)pkw[0][0], sl1);
    unsigned c01 = (unsigned)__shfl((int)pkw[0][1], sl1);
    unsigned c10 = (unsigned)__shfl((int)pkw[1][0], sl1);
    unsigned c11 = (unsigned)__shfl((int)pkw[1][1], sl1);
    unsigned e00 = (unsigned)__shfl((int)pkw[2][0], sl0);
    unsigned e01 = (unsigned)__shfl((int)pkw[2][1], sl0);
    unsigned e10 = (unsigned)__shfl((int)pkw[3][0], sl0);
    unsigned e11 = (unsigned)__shfl((int)pkw[3][1], sl0);
    unsigned g00 = (unsigned)__shfl((int)pkw[2][0], sl1);
    unsigned g01 = (unsigned)__shfl((int)pkw[2][1], sl1);
    unsigned g10 = (unsigned)__shfl((int)pkw[3][0], sl1);
    unsigned g11 = (unsigned)__shfl((int)pkw[3][1], sl1);
    union { unsigned u[4]; bf16x8 v; } B0, B1;
    B0.u[0] = sel ? a10 : a00;
    B0.u[1] = sel ? a11 : a01;
    B0.u[2] = sel ? c10 : c00;
    B0.u[3] = sel ? c11 : c01;
    B1.u[0] = sel ? e10 : e00;
    B1.u[1] = sel ? e11 : e01;
    B1.u[2] = sel ? g10 : g00;
    B1.u[3] = sel ? g11 : g01;

    __builtin_amdgcn_s_setprio(1);
#pragma unroll
    for (int db = 0; db < 4; db++) {
      bf16x8 bv0 = *(const bf16x8*)&vtl[cur][(db * 16 + l15) * 64 + rs0];
      bf16x8 bv1 = *(const bf16x8*)&vtl[cur][(db * 16 + l15) * 64 + rs1];
      accy[db] = mfma16(bv0, B0.v, accy[db]);
      accy[db] = mfma16(bv1, B1.v, accy[db]);
    }
    accl = mfma16(ones, B0.v, accl);
    accl = mfma16(ones, B1.v, accl);
    __builtin_amdgcn_s_setprio(0);

    if (kt + 1 < NT) {
      const int nxt = cur ^ 1;
      *(bf16x8*)&ktl[nxt][sr * 64 + ssw] = kr;
      *(bf16x8*)&vtl[nxt][sr * 64 + ssw] = vp;
    }
    __syncthreads();
  }

  const float il = 1.f / accl[0];

#pragma unroll
  for (int db = 0; db < 4; db++) {
    bf16x4 o;
#pragma unroll
    for (int r = 0; r < 4; r++) o[r] = (short)f2bf(accy[db][r] * il);
    *(bf16x4*)(y_pre + (size_t)(b * TX + qbase + l15) * CC + h * HD + db * 16 +
               4 * lhi) = o;
  }
  if (lhi == 0) {
    int idx = (b * NH + h) * TX + qbase + l15;
    m_ws[idx] = mrun;
    il_ws[idx] = il;
  }
}

// ---------------------------------------------------------------------------
// att_mean v6 (unchanged; its default layout already co-locates Q-sharers on
// one XCD — regrouping by K would thrash Q). 8 waves = 128 q-rows x 64 keys;
// per-head K tile in XOR-swizzled LDS, double-buffered, one barrier/head.
// ---------------------------------------------------------------------------
__global__ __launch_bounds__(512) void att_mean_k(
    const unsigned short* __restrict__ Qw, const unsigned short* __restrict__ Kw,
    const float* __restrict__ m_ws, const float* __restrict__ il_ws,
    float* __restrict__ attm) {
  __shared__ __align__(16) unsigned short ktl[2][64 * 64];  // [buf][key][d] swz

  const int tid = threadIdx.x;
  const int wid = tid >> 6, l = tid & 63, l15 = l & 15, lhi = l >> 4;
  const int qbase = blockIdx.x * 128 + wid * 16;  // x = q tile (fastest)
  const int keyb = blockIdx.y * 64;               // y = key tile
  const int b = blockIdx.z;

  const unsigned short* Qb = Qw + (size_t)b * NH * TX * HD;
  const unsigned short* Kb = Kw + (size_t)b * NH * TC * HD;

  const int rs0 = (lhi ^ (l15 & 7)) << 3;
  const int rs1 = ((lhi ^ 4) ^ (l15 & 7)) << 3;

  const int sr = tid >> 3;
  const int ssw = ((tid & 7) ^ (sr & 7)) << 3;
  const int sc0 = (tid & 7) * 8;

  bf16x8 aq0[2], aq1[2];
  f32x4 mm[2], ii[2];

  auto load_q = [&](int h, int p) {
    const unsigned short* qp =
        Qb + ((size_t)h * TX + qbase + l15) * HD + lhi * 8;
    aq0[p] = *(const bf16x8*)qp;
    aq1[p] = *(const bf16x8*)(qp + 32);
    mm[p] = *(const f32x4*)(m_ws + (size_t)(b * NH + h) * TX + qbase + 4 * lhi);
    ii[p] = *(const f32x4*)(il_ws + (size_t)(b * NH + h) * TX + qbase + 4 * lhi);
  };

  bf16x8 kr = *(const bf16x8*)(Kb + ((size_t)keyb + sr) * HD + sc0);
  load_q(0, 0);
  *(bf16x8*)&ktl[0][sr * 64 + ssw] = kr;
  __syncthreads();

  f32x4 am[4];
#pragma unroll
  for (int kb = 0; kb < 4; kb++) am[kb] = zero4();

#pragma unroll
  for (int h = 0; h < NH; h++) {
    const int cur = h & 1;

    if (h + 1 < NH) {
      kr = *(const bf16x8*)(Kb + ((size_t)(h + 1) * TC + keyb + sr) * HD + sc0);
      load_q(h + 1, cur ^ 1);
    }

#pragma unroll
    for (int kb = 0; kb < 4; kb++) {
      bf16x8 bk0 = *(const bf16x8*)&ktl[cur][(kb * 16 + l15) * 64 + rs0];
      bf16x8 bk1 = *(const bf16x8*)&ktl[cur][(kb * 16 + l15) * 64 + rs1];
      f32x4 a = zero4();
      a = mfma16(aq0[cur], bk0, a);
      a = mfma16(aq1[cur], bk1, a);
#pragma unroll
      for (int r = 0; r < 4; r++)
        am[kb][r] += exp2f(a[r] - mm[cur][r]) * ii[cur][r];
    }

    if (h + 1 < NH) {
      const int nxt = cur ^ 1;
      *(bf16x8*)&ktl[nxt][sr * 64 + ssw] = kr;
    }
    __syncthreads();
  }

#pragma unroll
  for (int kb = 0; kb < 4; kb++)
#pragma unroll
    for (int r = 0; r < 4; r++) {
      int trow = qbase + 4 * lhi + r;
      attm[(size_t)(b * TX + trow) * TC + keyb + kb * 16 + l15] = am[kb][r] * 0.125f;
    }
}

// ---------------------------------------------------------------------------
extern "C" void kernel_launch(void* const* d_in, const int* in_sizes, int n_in,
                              void* d_out, int out_size, void* d_ws, size_t ws_size,
                              hipStream_t stream) {
  const float* x   = (const float*)d_in[0];
  const float* ctx = (const float*)d_in[1];
  const float* Wq  = (const float*)d_in[2];
  const float* bq  = (const float*)d_in[3];
  const float* Wk  = (const float*)d_in[4];
  const float* bk  = (const float*)d_in[5];
  const float* Wv  = (const float*)d_in[6];
  const float* bv  = (const float*)d_in[7];
  const float* Wo  = (const float*)d_in[8];
  const float* bo  = (const float*)d_in[9];

  float* y_out = (float*)d_out;                       // (B, Tx, C)
  float* attm  = y_out + (size_t)Bb * TX * CC;        // (B, Tx, Tc)

  // workspace layout (16B-aligned), ~53 MB total:
  unsigned short* q_ws = (unsigned short*)d_ws;                  // B*NH*TX*HD bf16
  unsigned short* k_ws = q_ws + (size_t)Bb * NH * TX * HD;       // B*NH*TC*HD bf16
  unsigned short* v_ws = k_ws + (size_t)Bb * NH * TC * HD;       // B*NH*TC*HD bf16 (V^T)
  float* m_ws  = (float*)(v_ws + (size_t)Bb * NH * TC * HD);     // B*NH*TX f32
  float* il_ws = m_ws + (size_t)Bb * NH * TX;                    // B*NH*TX f32
  unsigned short* y_pre = (unsigned short*)(il_ws + (size_t)Bb * NH * TX);  // B*TX*CC bf16
  unsigned short* wb = y_pre + (size_t)Bb * TX * CC;             // 4x CC*CC bf16
  unsigned short* wbq = wb, *wbk = wb + CC * CC, *wbv = wb + 2 * CC * CC,
                 *wbo = wb + 3 * CC * CC;

  // bf16 input overlays (consumed before their regions are overwritten):
  unsigned short* xb = k_ws;              // read by Q-GEMM, then kv_gemm overwrites
  unsigned short* cb = (unsigned short*)attm;  // read by kv_gemm, att_mean_k overwrites

  const int NX8 = Bb * TX * CC / 8, NC8 = Bb * TC * CC / 8, NW8 = CC * CC / 8;
  cvt_all<<<dim3(2048), 256, 0, stream>>>(x, xb, NX8, ctx, cb, NC8,
                                          Wq, wbq, NW8, Wk, wbk, NW8,
                                          Wv, wbv, NW8, Wo, wbo, NW8);

  // Q pre-scaled by log2(e)/sqrt(hd) so attention exp is bare v_exp_f32 (2^x)
  gemm64m<0><<<dim3(CC / 128, (Bb * TX) / 64), 256, 0, stream>>>(
      xb, wbq, bq, q_ws, 10, 0.125f * LOG2E);
  kv_gemm128<<<dim3(CC / 128, (Bb * TC) / 128), 256, 0, stream>>>(
      cb, wbk, wbv, bk, bv, k_ws, v_ws);
  attn_fwd<<<dim3(TX / 128, NH, Bb), 512, 0, stream>>>(q_ws, k_ws, v_ws, y_pre, m_ws, il_ws);
  att_mean_k<<<dim3(TX / 128, TC / 64, Bb), 512, 0, stream>>>(q_ws, k_ws, m_ws, il_ws, attm);
  gemm64m<1><<<dim3(CC / 128, (Bb * TX) / 64), 256, 0, stream>>>(
      y_pre, wbo, bo, y_out, 10, 1.0f);
}